// Round 4
// baseline (923.186 us; speedup 1.0000x reference)
//
#include <hip/hip_runtime.h>

// Problem constants (fixed by reference setup_inputs)
constexpr int T_DIM = 10, C_DIM = 3, H_DIM = 512, W_DIM = 512;
constexpr int PT = 2, PS = 7;
constexpr int ELEM_PER_Q = PT * C_DIM * PS * PS;  // 294
constexpr int HALF      = C_DIM * PS * PS;        // 147 (one dt-slice of a patch)
constexpr int TILE = 38;                           // exclusive output tile (h,w)
constexpr int NTH = 14, NTW = 14;                  // spatial tiles: ceil(512/38)=14
constexpr int NBINS = T_DIM * NTH * NTW;           // 1960 (ts, th, tw) — per OUTPUT tile
constexpr int BINPAD = 2048;
constexpr int QMASK = (1 << 18) - 1;               // Q = 262144 = 2^18

// d_ws layout (ints): counts[2048] | offsets[2048] | cursors[2048] | list[<=8Q]
// Entry: q | (dt << 18). Expansion: 2 t-slices x (1..2 h-tiles) x (1..2 w-tiles).

__global__ __launch_bounds__(256) void ScatterNL_hist(
    const int* __restrict__ qinds, int Q, int* __restrict__ counts)
{
    __shared__ int hloc[NBINS];
    for (int i = threadIdx.x; i < NBINS; i += blockDim.x) hloc[i] = 0;
    __syncthreads();
    int stride = gridDim.x * blockDim.x;
    for (int q = blockIdx.x * blockDim.x + threadIdx.x; q < Q; q += stride) {
        int t = qinds[3*q], h = qinds[3*q+1], w = qinds[3*q+2];
        int th0 = h / TILE, th1 = (h + PS - 1) / TILE;
        int tw0 = w / TILE, tw1 = (w + PS - 1) / TILE;
        for (int ts = t; ts < t + PT; ++ts)            // ts <= 9 always valid
            for (int th = th0; th <= th1; ++th)
                for (int tw = tw0; tw <= tw1; ++tw)
                    atomicAdd(&hloc[(ts * NTH + th) * NTW + tw], 1);
    }
    __syncthreads();
    for (int i = threadIdx.x; i < NBINS; i += blockDim.x)
        if (hloc[i]) atomicAdd(&counts[i], hloc[i]);
}

// 256 threads, each owns 8 consecutive bins (256*8=2048 >= 1960).
__global__ __launch_bounds__(256) void ScatterNL_scan(
    const int* __restrict__ counts, int* __restrict__ offsets,
    int* __restrict__ cursors)
{
    __shared__ int buf[2][256];
    int tid = threadIdx.x;
    int base = tid * 8;
    int loc[8];
    int s = 0;
    #pragma unroll
    for (int i = 0; i < 8; ++i) {
        int b = base + i;
        int v = (b < NBINS) ? counts[b] : 0;
        loc[i] = s;
        s += v;
    }
    buf[0][tid] = s;
    __syncthreads();
    int src = 0;
    for (int d = 1; d < 256; d <<= 1) {
        int x = buf[src][tid] + ((tid >= d) ? buf[src][tid - d] : 0);
        buf[src ^ 1][tid] = x;
        __syncthreads();
        src ^= 1;
    }
    int excl = (tid == 0) ? 0 : buf[src][tid - 1];
    #pragma unroll
    for (int i = 0; i < 8; ++i) {
        int b = base + i;
        if (b < NBINS) {
            offsets[b] = excl + loc[i];
            cursors[b] = excl + loc[i];
        }
    }
    if (tid == 255) offsets[NBINS] = buf[src][255];
}

__global__ __launch_bounds__(256) void ScatterNL_fill(
    const int* __restrict__ qinds, int Q, int* __restrict__ cursors,
    int* __restrict__ list)
{
    int stride = gridDim.x * blockDim.x;
    for (int q = blockIdx.x * blockDim.x + threadIdx.x; q < Q; q += stride) {
        int t = qinds[3*q], h = qinds[3*q+1], w = qinds[3*q+2];
        int th0 = h / TILE, th1 = (h + PS - 1) / TILE;
        int tw0 = w / TILE, tw1 = (w + PS - 1) / TILE;
        for (int ts = t; ts < t + PT; ++ts) {
            int ent = q | ((ts - t) << 18);
            for (int th = th0; th <= th1; ++th)
                for (int tw = tw0; tw <= tw1; ++tw) {
                    int pos = atomicAdd(&cursors[(ts * NTH + th) * NTW + tw], 1);
                    list[pos] = ent;
                }
        }
    }
}

__global__ __launch_bounds__(256) void ScatterNL_accum(
    const float* __restrict__ vid, const float* __restrict__ patches,
    const int* __restrict__ qinds, const int* __restrict__ offsets,
    const int* __restrict__ list, float* __restrict__ out)
{
    __shared__ float acc[C_DIM * TILE * TILE];   // 17,328 B -> 8 blocks/CU (wave-capped)

    int bid = blockIdx.x;
    int ts  = bid / (NTH * NTW);
    int r   = bid % (NTH * NTW);
    int th  = r / NTW, tw = r % NTW;
    int h0  = th * TILE, w0 = tw * TILE;
    int THe = min(TILE, H_DIM - h0);
    int TWe = min(TILE, W_DIM - w0);

    for (int i = threadIdx.x; i < C_DIM * TILE * TILE; i += blockDim.x)
        acc[i] = 0.f;
    __syncthreads();

    const int lane = threadIdx.x & 63;
    const int wv   = threadIdx.x >> 6;
    const int NW   = blockDim.x >> 6;            // 4 waves

    // Per-lane (c,i,j) for patch element k = lane + 64*s (s=0,1,2; 147 total).
    int cc[3], ii[3], jj[3];
    #pragma unroll
    for (int s = 0; s < 3; ++s) {
        int k = lane + 64 * s;
        int kk = (k < HALF) ? k : 0;
        cc[s] = kk / 49;
        int rr = kk % 49;
        ii[s] = rr / 7;
        jj[s] = rr % 7;
    }
    const bool v2ok = (lane < HALF - 128);       // lane < 19

    int start = offsets[bid], end = offsets[bid + 1];
    int nb = (end - start + 63) >> 6;
    for (int bi = wv; bi < nb; bi += NW) {
        int b0 = start + (bi << 6);
        int n  = min(64, end - b0);
        int ent = 0, hw = 0;
        if (lane < n) {
            ent = list[b0 + lane];               // coalesced burst
            int q = ent & QMASK;
            hw = (qinds[3*q+1] << 16) | qinds[3*q+2];  // L2-hot 64-way gather
        }
        // Software pipeline: 4 queries' payloads in flight per step.
        for (int i = 0; i < n; i += 4) {
            float v[4][3];
            int hws[4];
            bool ok[4];
            #pragma unroll
            for (int j = 0; j < 4; ++j) {
                int idx = i + j;
                ok[j]  = (idx < n);
                int sl = ok[j] ? idx : 0;
                int es = __shfl(ent, sl);
                hws[j] = __shfl(hw, sl);
                int qs  = es & QMASK;
                int dts = (es >> 18) & 1;
                const float* bp = patches + (size_t)qs * ELEM_PER_Q + dts * HALF;
                v[j][0] = bp[lane];
                v[j][1] = bp[lane + 64];
                v[j][2] = v2ok ? bp[lane + 128] : 0.f;
            }
            #pragma unroll
            for (int j = 0; j < 4; ++j) {
                if (!ok[j]) continue;            // wave-uniform
                int qhs = hws[j] >> 16, qws = hws[j] & 0xffff;
                #pragma unroll
                for (int s = 0; s < 3; ++s) {
                    bool lv = (s < 2) || v2ok;
                    int hh = qhs + ii[s] - h0;
                    int ww = qws + jj[s] - w0;
                    if (lv && hh >= 0 && hh < THe && ww >= 0 && ww < TWe)
                        atomicAdd(&acc[(cc[s] * TILE + hh) * TILE + ww], v[j][s]);
                }
            }
        }
    }
    __syncthreads();

    // Exclusive write-out: out = vid2fill + acc. Each output element written once.
    #pragma unroll
    for (int c = 0; c < C_DIM; ++c) {
        for (int y = wv; y < THe; y += NW) {
            if (lane < TWe) {
                size_t o = (((size_t)ts * C_DIM + c) * H_DIM + (h0 + y)) * W_DIM + w0 + lane;
                out[o] = vid[o] + acc[(c * TILE + y) * TILE + lane];
            }
        }
    }
}

extern "C" void kernel_launch(void* const* d_in, const int* in_sizes, int n_in,
                              void* d_out, int out_size, void* d_ws, size_t ws_size,
                              hipStream_t stream) {
    const float* vid     = (const float*)d_in[0];
    const float* patches = (const float*)d_in[1];
    const int*   qinds   = (const int*)d_in[2];
    float* out = (float*)d_out;
    int Q = in_sizes[2] / 3;

    int* ws      = (int*)d_ws;
    int* counts  = ws;
    int* offsets = ws + BINPAD;
    int* cursors = ws + 2 * BINPAD;
    int* list    = ws + 3 * BINPAD;               // <= 8*Q entries (avg ~2.65*Q)

    hipMemsetAsync(counts, 0, BINPAD * sizeof(int), stream);
    ScatterNL_hist<<<256, 256, 0, stream>>>(qinds, Q, counts);
    ScatterNL_scan<<<1, 256, 0, stream>>>(counts, offsets, cursors);
    ScatterNL_fill<<<256, 256, 0, stream>>>(qinds, Q, cursors, list);
    ScatterNL_accum<<<NBINS, 256, 0, stream>>>(
        vid, patches, qinds, offsets, list, out);
}